// Round 10
// baseline (201.459 us; speedup 1.0000x reference)
//
#include <hip/hip_runtime.h>

// SelfAttention: x[2,2048,1024] fp32 -> qkv -> flash attention -> proj -> fp32.
// R21: R20 + split-K=2 proj. Proj was ~40-49us at only ~190 TF (8 MFMA per
// barrier window at MT=2; MT=4 alone drops to 1 block/CU). Split-K=2 gives
// MT=4 density (16 MFMA/window) AND 512 blocks (2/CU): grid (8,32,2), each
// block K=512, fp32 atomicAdd epilogue (2 order-independent adds/element,
// bias from kz=0 only). out zero-init folded into cvt3 (1M threads = 4M
// floats, one float4 each). attn (R17, 49.8us) and qkv (BK=32 MT=4) untouched.

typedef __bf16 bf16x8 __attribute__((ext_vector_type(8)));
typedef float f32x4 __attribute__((ext_vector_type(4)));
typedef float f32x16 __attribute__((ext_vector_type(16)));

#if __has_builtin(__builtin_amdgcn_exp2f)
#define EXP2F(x) __builtin_amdgcn_exp2f(x)
#else
#define EXP2F(x) __expf((x)*0.69314718056f)
#endif

__device__ inline float bf2f(unsigned short u) {
    union { unsigned int i; float f; } v; v.i = ((unsigned int)u) << 16; return v.f;
}
__device__ inline unsigned short f2bf(float f) {
    union { float f; unsigned int i; } v; v.f = f;
    unsigned int u = v.i;
    return (unsigned short)((u + 0x7FFFu + ((u >> 16) & 1u)) >> 16);  // RNE
}
__device__ inline unsigned int pack2(float lo, float hi) {
    return (unsigned int)f2bf(lo) | ((unsigned int)f2bf(hi) << 16);
}
__device__ inline uint4 ld8(const unsigned short* p) { return *(const uint4*)p; }
__device__ inline uint4 ld8(const float* p) {
    float4 a = *(const float4*)p;
    float4 b = *(const float4*)(p + 4);
    uint4 r;
    r.x = pack2(a.x, a.y); r.y = pack2(a.z, a.w);
    r.z = pack2(b.x, b.y); r.w = pack2(b.z, b.w);
    return r;
}

__device__ inline void gld16(const unsigned short* g, unsigned short* l) {
    __builtin_amdgcn_global_load_lds(
        (const __attribute__((address_space(1))) unsigned int*)g,
        (__attribute__((address_space(3))) unsigned int*)l, 16, 0, 0);
}

// fused fp32->bf16 conversion of x, qkv_w, proj_w + zero-init of out
__global__ __launch_bounds__(256) void cvt3_kernel(const float* __restrict__ x,
                                                   const float* __restrict__ qw,
                                                   const float* __restrict__ pw,
                                                   unsigned short* __restrict__ xb,
                                                   unsigned short* __restrict__ qwb,
                                                   unsigned short* __restrict__ pwb,
                                                   float4* __restrict__ outz) {
    int i = blockIdx.x * blockDim.x + threadIdx.x;  // 0 .. 1048575
    const int NX = 4096 * 1024 / 8;      // 524288
    const int NQ = 3072 * 1024 / 8;      // 393216
    if (i < NX) {
        *(uint4*)(xb + (size_t)i * 8) = ld8(x + (size_t)i * 8);
    } else if (i < NX + NQ) {
        int j = i - NX;
        *(uint4*)(qwb + (size_t)j * 8) = ld8(qw + (size_t)j * 8);
    } else {
        int j = i - NX - NQ;
        *(uint4*)(pwb + (size_t)j * 8) = ld8(pw + (size_t)j * 8);
    }
    // zero out (4096*1024 fp32 = 1048576 float4 = exactly one per thread)
    outz[i] = (float4){0.f, 0.f, 0.f, 0.f};
}

// ---------------------------------------------------------------------------
// FAST GEMM (m97 recipe): all-bf16, (MT*32)x128 tile, BK=32, unpadded LDS,
// global_load_lds width-16 staging. C = A[M,K] * W[N,K]^T (+bias).
// XCD-swizzled block remap (requires gridX*gridY % 8 == 0).
// SPLITK>1: blockIdx.z selects a K/SPLITK slice; fp32 atomicAdd epilogue
// (requires OUT_F32 and a zero-initialized C; bias added by kz==0 only).
// ---------------------------------------------------------------------------
template <int WITH_BIAS, int OUT_F32, int MT, int SPLITK>
__global__ __launch_bounds__(256) void gemm_fast(const unsigned short* __restrict__ A,
                                                 const unsigned short* __restrict__ W,
                                                 const float* __restrict__ bias,
                                                 void* __restrict__ Cv,
                                                 int M, int N, int K) {
    constexpr int BM = MT * 32;
    __shared__ unsigned short As[BM * 32];
    __shared__ unsigned short Bs[128 * 32];

    const int tid = threadIdx.x;
    const int wave = tid >> 6, lane = tid & 63;
    const int l15 = lane & 15, quad = lane >> 4;
    const int waveM = wave >> 1, waveN = wave & 1;

    // XCD swizzle: cluster consecutive work on one XCD's L2 (per kz slice)
    const int nbx = gridDim.x;
    const int L = blockIdx.y * nbx + blockIdx.x;
    const int nwg = nbx * gridDim.y;
    const int w = (L & 7) * (nwg >> 3) + (L >> 3);
    const int bm = (w / nbx) * BM, bn = (w % nbx) * 128;

    const int kz = (SPLITK > 1) ? blockIdx.z : 0;
    const int k0 = kz * (K / SPLITK), k1 = k0 + K / SPLITK;

    const int lr = lane >> 2;
    const int lc = (lane & 3) * 8;

    f32x4 acc[MT][4];
    for (int i = 0; i < MT; i++)
        for (int j = 0; j < 4; j++) acc[i][j] = (f32x4){0.f, 0.f, 0.f, 0.f};

    for (int kb = k0; kb < k1; kb += 32) {
        for (int p = 0; p < BM / 64; p++)
            gld16(A + (size_t)(bm + wave * (BM / 4) + p * 16 + lr) * K + kb + lc,
                  &As[(wave * (BM / 4) + p * 16) * 32]);
        gld16(W + (size_t)(bn + wave * 32 + lr) * K + kb + lc, &Bs[(wave * 32) * 32]);
        gld16(W + (size_t)(bn + wave * 32 + 16 + lr) * K + kb + lc, &Bs[(wave * 32 + 16) * 32]);
        __syncthreads();

        const int kcol = quad * 8;
        bf16x8 af[MT], bf[4];
        for (int mt = 0; mt < MT; mt++)
            af[mt] = *(const bf16x8*)(&As[(waveM * (MT * 16) + mt * 16 + l15) * 32 + kcol]);
        for (int nt = 0; nt < 4; nt++)
            bf[nt] = *(const bf16x8*)(&Bs[(waveN * 64 + nt * 16 + l15) * 32 + kcol]);
        for (int mt = 0; mt < MT; mt++)
            for (int nt = 0; nt < 4; nt++)
                acc[mt][nt] = __builtin_amdgcn_mfma_f32_16x16x32_bf16(af[mt], bf[nt], acc[mt][nt], 0, 0, 0);
        __syncthreads();
    }

    for (int mt = 0; mt < MT; mt++) {
        for (int nt = 0; nt < 4; nt++) {
            int col = bn + waveN * 64 + nt * 16 + l15;
            float bv = (WITH_BIAS && kz == 0) ? bias[col] : 0.f;
            for (int r = 0; r < 4; r++) {
                int row = bm + waveM * (MT * 16) + mt * 16 + quad * 4 + r;
                float v = acc[mt][nt][r] + bv;
                if (SPLITK > 1) {
                    atomicAdd(&((float*)Cv)[(size_t)row * N + col], v);
                } else if (OUT_F32) {
                    ((float*)Cv)[(size_t)row * N + col] = v;
                } else {
                    ((unsigned short*)Cv)[(size_t)row * N + col] = f2bf(v);
                }
            }
        }
    }
}

// ---------------------------------------------------------------------------
// FALLBACK GEMM (R8): convert-in-staging, fp32/bf16 inputs.
// ---------------------------------------------------------------------------
template <int WITH_BIAS, int OUT_F32, typename TA, typename TW>
__global__ __launch_bounds__(256) void gemm_bt(const TA* __restrict__ A,
                                               const TW* __restrict__ W,
                                               const float* __restrict__ bias,
                                               void* __restrict__ Cv,
                                               int M, int N, int K) {
    const int LDSS = 40;
    __shared__ unsigned short As[128 * 40];
    __shared__ unsigned short Bs[128 * 40];

    const int tid = threadIdx.x;
    const int wave = tid >> 6, lane = tid & 63;
    const int l15 = lane & 15, quad = lane >> 4;
    const int waveM = wave >> 1, waveN = wave & 1;
    const int bm = blockIdx.y * 128, bn = blockIdx.x * 128;

    f32x4 acc[4][4];
    for (int i = 0; i < 4; i++)
        for (int j = 0; j < 4; j++) acc[i][j] = (f32x4){0.f, 0.f, 0.f, 0.f};

    for (int kb = 0; kb < K; kb += 32) {
        for (int c = tid; c < 512; c += 256) {
            int row = c >> 2, k0 = (c & 3) * 8;
            *(uint4*)(&As[row * LDSS + k0]) = ld8(A + (size_t)(bm + row) * K + kb + k0);
            *(uint4*)(&Bs[row * LDSS + k0]) = ld8(W + (size_t)(bn + row) * K + kb + k0);
        }
        __syncthreads();

        const int kcol = quad * 8;
        bf16x8 af[4], bf[4];
        for (int mt = 0; mt < 4; mt++)
            af[mt] = *(const bf16x8*)(&As[(waveM * 64 + mt * 16 + l15) * LDSS + kcol]);
        for (int nt = 0; nt < 4; nt++)
            bf[nt] = *(const bf16x8*)(&Bs[(waveN * 64 + nt * 16 + l15) * LDSS + kcol]);
        for (int mt = 0; mt < 4; mt++)
            for (int nt = 0; nt < 4; nt++)
                acc[mt][nt] = __builtin_amdgcn_mfma_f32_16x16x32_bf16(af[mt], bf[nt], acc[mt][nt], 0, 0, 0);
        __syncthreads();
    }

    for (int mt = 0; mt < 4; mt++) {
        for (int nt = 0; nt < 4; nt++) {
            int col = bn + waveN * 64 + nt * 16 + l15;
            float bv = WITH_BIAS ? bias[col] : 0.f;
            for (int r = 0; r < 4; r++) {
                int row = bm + waveM * 64 + mt * 16 + quad * 4 + r;
                float v = acc[mt][nt][r] + bv;
                if (OUT_F32) ((float*)Cv)[(size_t)row * N + col] = v;
                else ((unsigned short*)Cv)[(size_t)row * N + col] = f2bf(v);
            }
        }
    }
}

// ---------------------------------------------------------------------------
// Flash attention (R17, verified 49.8us): swapped-QK^T 32x32 MFMA,
// in-register P, XCD work-clustering (same-head q-tiles share an XCD L2).
// Block = 512 threads (8 waves) per (b, h, 128-q tile). Wave (qt, par).
// ---------------------------------------------------------------------------
__global__ __launch_bounds__(512, 4) void attn_kernel(const unsigned short* __restrict__ qkv,
                                                      unsigned short* __restrict__ y) {
    // bijective XCD clustering over 512 blocks: XCD k gets contiguous work ids
    const int L = blockIdx.x + 16 * (blockIdx.y + 16 * blockIdx.z);
    const int wid = (L & 7) * 64 + (L >> 3);
    const int q0 = (wid & 15) * 128;
    const int head = wid >> 4;            // 0..31
    const int h = head & 15, b = head >> 4;

    const int tid = threadIdx.x;
    const int wave = tid >> 6, lane = tid & 63;
    const int l31 = lane & 31, half = lane >> 5;
    const int qt = wave >> 1, par = wave & 1;

    // LDS: staging Ks[128][64] + Vt[64][128] (32 KiB), reused as combine
    // buffers (obuf 4x2048 f32 + lbuf 4x32 f32 = 33280 B) after the loop.
    __shared__ __align__(16) unsigned short smem[16640];
    unsigned short* Ks = smem;           // 8192 shorts
    unsigned short* Vt = smem + 8192;    // 8192 shorts

    const size_t bbase = (size_t)b * 2048;
    const float C = 0.18033688f;  // 0.125 * log2(e)

    // ---- Q fragments (B operand), pre-scaled, straight from global ----
    bf16x8 qf[4];
    {
        const unsigned short* qrow =
            qkv + (bbase + q0 + qt * 32 + l31) * 3072 + h * 64 + half * 8;
        #pragma unroll
        for (int t = 0; t < 4; t++) {
            uint4 v = *(const uint4*)(qrow + t * 16);
            const unsigned short* pv = (const unsigned short*)&v;
            union { bf16x8 v8; unsigned int u[4]; } o;
            #pragma unroll
            for (int j = 0; j < 4; j++)
                o.u[j] = pack2(bf2f(pv[2 * j]) * C, bf2f(pv[2 * j + 1]) * C);
            qf[t] = o.v8;
        }
    }

    // ---- staging coords ----
    const int kr = tid >> 3;     // 0..63: K row (and +64); V key-pair index
    const int cb = tid & 7;      // 16B column block (K) / d-group (V)
    const int sk = (kr ^ (kr >> 3)) & 7;            // K swizzle (same for kr+64)
    const unsigned short* kptr = qkv + (bbase + kr) * 3072 + h * 64 + 1024 + cb * 8;
    const unsigned short* vptr = qkv + (bbase + 2 * kr) * 3072 + h * 64 + 2048 + cb * 8;

    f32x16 o[2];
    #pragma unroll
    for (int j = 0; j < 16; j++) { o[0][j] = 0.f; o[1][j] = 0.f; }
    float Lp = 0.f;

    // prefetch chunk 0
    uint4 kA0 = *(const uint4*)(kptr);
    uint4 kA1 = *(const uint4*)(kptr + (size_t)64 * 3072);
    uint4 vA0 = *(const uint4*)(vptr);
    uint4 vA1 = *(const uint4*)(vptr + 3072);

    for (int kb = 0; kb < 2048; kb += 128) {
        __syncthreads();  // previous chunk's LDS consumers done

        // commit prefetched K (swizzled 16B blocks)
        *(uint4*)(&Ks[kr * 64 + ((cb ^ sk) * 8)]) = kA0;
        *(uint4*)(&Ks[(kr + 64) * 64 + ((cb ^ sk) * 8)]) = kA1;
        // commit prefetched V, transposed: Vt[d][key], swizzled dwords
        {
            const unsigned short* p0 = (const unsigned short*)&vA0;
            const unsigned short* p1 = (const unsigned short*)&vA1;
            #pragma unroll
            for (int j = 0; j < 8; j++) {
                unsigned int w = (unsigned int)p0[j] | ((unsigned int)p1[j] << 16);
                *(unsigned int*)(&Vt[(cb * 8 + j) * 128 + ((2 * kr) ^ ((j ^ cb) * 8))]) = w;
            }
        }
        __syncthreads();

        // prefetch next chunk (loads in flight across compute below)
        int nkb = (kb + 128) & 2047;
        size_t koff = (size_t)nkb * 3072;
        kA0 = *(const uint4*)(kptr + koff);
        kA1 = *(const uint4*)(kptr + koff + (size_t)64 * 3072);
        vA0 = *(const uint4*)(vptr + koff);
        vA1 = *(const uint4*)(vptr + koff + 3072);

        // two 32-key chunks from this wave's key-half
        #pragma unroll
        for (int ci = 0; ci < 2; ci++) {
            const int kc = (par * 2 + ci) * 32;

            // ---- S^T = K * Q^T : lane -> P row for q = l31 ----
            const int key = kc + l31;
            const int skk = (key ^ (key >> 3)) & 7;
            const unsigned short* kbase = &Ks[key * 64];
            f32x16 s;
            #pragma unroll
            for (int j = 0; j < 16; j++) s[j] = 0.f;
            __builtin_amdgcn_s_setprio(1);
            #pragma unroll
            for (int t = 0; t < 4; t++) {
                bf16x8 kf = *(const bf16x8*)(kbase + (((t * 2 + half) ^ skk) * 8));
                s = __builtin_amdgcn_mfma_f32_32x32x16_bf16(kf, qf[t], s, 0, 0, 0);
            }
            __builtin_amdgcn_s_setprio(0);

            // ---- p = 2^s (unnormalized), l partial via VALU tree ----
            float p[16];
            #pragma unroll
            for (int r = 0; r < 16; r++) p[r] = EXP2F(s[r]);
            {
                float t0 = (p[0] + p[1]) + (p[2] + p[3]);
                float t1 = (p[4] + p[5]) + (p[6] + p[7]);
                float t2 = (p[8] + p[9]) + (p[10] + p[11]);
                float t3 = (p[12] + p[13]) + (p[14] + p[15]);
                Lp += (t0 + t1) + (t2 + t3);
            }

            // ---- pack to bf16 + permlane32_swap => PV A-fragments ----
            unsigned int a0, a1, a2, a3, a4, a5, a6, a7;
            asm("v_cvt_pk_bf16_f32 %0, %1, %2" : "=v"(a0) : "v"(p[0]), "v"(p[1]));
            asm("v_cvt_pk_bf16_f32 %0, %1, %2" : "=v"(a1) : "v"(p[2]), "v"(p[3]));
            asm("v_cvt_pk_bf16_f32 %0, %1, %2" : "=v"(a2) : "v"(p[4]), "v"(p[5]));
            asm("v_cvt_pk_bf16_f32 %0, %1, %2" : "=v"(a3) : "v"(p[6]), "v"(p[7]));
            asm("v_cvt_pk_bf16_f32 %0, %1, %2" : "=v"(a4) : "v"(p[8]), "v"(p[9]));
            asm("v_cvt_pk_bf16_f32 %0, %1, %2" : "=v"(a5) : "v"(p[10]), "v"(p[11]));
            asm("v_cvt_pk_bf16_f32 %0, %1, %2" : "=v"(a6) : "v"(p[12]), "v"(p[13]));
            asm("v_cvt_pk_bf16_f32 %0, %1, %2" : "=v"(a7) : "v"(p[14]), "v"(p[15]));
            asm("v_permlane32_swap_b32 %0, %1" : "+v"(a0), "+v"(a2));
            asm("v_permlane32_swap_b32 %0, %1" : "+v"(a1), "+v"(a3));
            asm("v_permlane32_swap_b32 %0, %1" : "+v"(a4), "+v"(a6));
            asm("v_permlane32_swap_b32 %0, %1" : "+v"(a5), "+v"(a7));
            union { bf16x8 v8; unsigned int u[4]; } f1, f2;
            f1.u[0] = a0; f1.u[1] = a1; f1.u[2] = a2; f1.u[3] = a3;
            f2.u[0] = a4; f2.u[1] = a5; f2.u[2] = a6; f2.u[3] = a7;

            // ---- O += P * V ----
            __builtin_amdgcn_s_setprio(1);
            #pragma unroll
            for (int dt = 0; dt < 2; dt++) {
                const int row = dt * 32 + l31;
                const int sv = (row ^ (row >> 3)) & 7;
                const unsigned short* vb = &Vt[row * 128];
                bf16x8 v0 = *(const bf16x8*)(vb + ((((kc >> 3) + half) ^ sv) * 8));
                bf16x8 v1 = *(const bf16x8*)(vb + ((((kc >> 3) + 2 + half) ^ sv) * 8));
                o[dt] = __builtin_amdgcn_mfma_f32_32x32x16_bf16(f1.v8, v0, o[dt], 0, 0, 0);
                o[dt] = __builtin_amdgcn_mfma_f32_32x32x16_bf16(f2.v8, v1, o[dt], 0, 0, 0);
            }
            __builtin_amdgcn_s_setprio(0);
        }
    }

    // ---- l: sum both lane-halves (q = l31 at every lane afterwards) ----
    float lx = Lp, ly = Lp;
    asm("v_permlane32_swap_b32 %0, %1" : "+v"(lx), "+v"(ly));
    float ltot31 = lx + ly;

    // ---- combine par=0 / par=1 partials through LDS ----
    __syncthreads();  // staging LDS no longer needed
    float* obuf = (float*)smem;                 // 4 x 2048 floats
    float* lbuf = ((float*)smem) + 8192;        // 4 x 32 floats
    if (par == 0) {
        float* ob = obuf + qt * 2048;
        #pragma unroll
        for (int dt = 0; dt < 2; dt++)
            #pragma unroll
            for (int r = 0; r < 16; r++) {
                int ql = (r & 3) + 8 * (r >> 2) + 4 * half;
                ob[ql * 64 + dt * 32 + l31] = o[dt][r];
            }
        if (half == 0) lbuf[qt * 32 + l31] = ltot31;
    }
    __syncthreads();
    if (par == 1) {
        const float* ob = obuf + qt * 2048;
        #pragma unroll
        for (int r = 0; r < 16; r++) {
            int ql = (r & 3) + 8 * (r >> 2) + 4 * half;
            float lsum = lbuf[qt * 32 + ql] + __shfl(ltot31, ql, 64);
            float rl = 1.0f / lsum;
            int row = q0 + qt * 32 + ql;
            #pragma unroll
            for (int dt = 0; dt < 2; dt++) {
                float v = ob[ql * 64 + dt * 32 + l31] + o[dt][r];
                y[(bbase + row) * 1024 + h * 64 + dt * 32 + l31] = f2bf(v * rl);
            }
        }
    }
}

extern "C" void kernel_launch(void* const* d_in, const int* in_sizes, int n_in,
                              void* d_out, int out_size, void* d_ws, size_t ws_size,
                              hipStream_t stream) {
    const float* x = (const float*)d_in[0];       // [4096,1024] fp32
    const float* qkv_w = (const float*)d_in[1];   // [3072,1024] fp32
    const float* proj_w = (const float*)d_in[2];  // [1024,1024] fp32
    const float* proj_b = (const float*)d_in[3];  // [1024] fp32
    float* out = (float*)d_out;                   // [4096,1024] fp32

    unsigned short* qkv = (unsigned short*)d_ws;               // 24 MiB
    unsigned short* slot2 = qkv + (size_t)4096 * 3072;         // 8 MiB: x_bf then y

    const size_t FAST_WS = (size_t)40 * 1024 * 1024;
    if (ws_size >= FAST_WS) {
        unsigned short* xb = slot2;                             // dead after qkv GEMM
        unsigned short* qwb = (unsigned short*)((char*)d_ws + 32 * 1024 * 1024);  // 6 MiB
        unsigned short* pwb = (unsigned short*)((char*)d_ws + 38 * 1024 * 1024);  // 2 MiB
        unsigned short* y = slot2;

        cvt3_kernel<<<4096, 256, 0, stream>>>(x, qkv_w, proj_w, xb, qwb, pwb,
                                              (float4*)out);

        gemm_fast<0, 0, 4, 1><<<dim3(24, 32), dim3(256), 0, stream>>>(
            xb, qwb, nullptr, qkv, 4096, 3072, 1024);
        attn_kernel<<<dim3(16, 16, 2), dim3(512), 0, stream>>>(qkv, y);
        gemm_fast<1, 1, 4, 2><<<dim3(8, 32, 2), dim3(256), 0, stream>>>(
            y, pwb, proj_b, out, 4096, 1024, 1024);
    } else {
        unsigned short* y = slot2;
        gemm_bt<0, 0, float, float><<<dim3(24, 32), dim3(256), 0, stream>>>(
            x, qkv_w, nullptr, qkv, 4096, 3072, 1024);
        attn_kernel<<<dim3(16, 16, 2), dim3(512), 0, stream>>>(qkv, y);
        gemm_bt<1, 1, unsigned short, float><<<dim3(8, 32), dim3(256), 0, stream>>>(
            y, proj_w, proj_b, out, 4096, 1024, 1024);
    }
}

// Round 11
// 192.043 us; speedup vs baseline: 1.0490x; 1.0490x over previous
//
#include <hip/hip_runtime.h>

// SelfAttention: x[2,2048,1024] fp32 -> qkv -> flash attention -> proj -> fp32.
// R22: split-K=2 proj via PLAIN-STORE partials + reduce (R21's atomics cost
// ~25us; the tiling was never the problem). proj: MT=4 grid(8,32,2)=512
// blocks (2/CU, 16 MFMA/window, 16 windows/block); kz=0 -> out (+bias),
// kz=1 -> fp32 partial in the dead qkv workspace region; addred: out += part
// (50MB traffic ~9us). cvt3 back to R20 form (no zero-init). attn (R17,
// 49.8us) and qkv (BK=32 MT=4) untouched.

typedef __bf16 bf16x8 __attribute__((ext_vector_type(8)));
typedef float f32x4 __attribute__((ext_vector_type(4)));
typedef float f32x16 __attribute__((ext_vector_type(16)));

#if __has_builtin(__builtin_amdgcn_exp2f)
#define EXP2F(x) __builtin_amdgcn_exp2f(x)
#else
#define EXP2F(x) __expf((x)*0.69314718056f)
#endif

__device__ inline float bf2f(unsigned short u) {
    union { unsigned int i; float f; } v; v.i = ((unsigned int)u) << 16; return v.f;
}
__device__ inline unsigned short f2bf(float f) {
    union { float f; unsigned int i; } v; v.f = f;
    unsigned int u = v.i;
    return (unsigned short)((u + 0x7FFFu + ((u >> 16) & 1u)) >> 16);  // RNE
}
__device__ inline unsigned int pack2(float lo, float hi) {
    return (unsigned int)f2bf(lo) | ((unsigned int)f2bf(hi) << 16);
}
__device__ inline uint4 ld8(const unsigned short* p) { return *(const uint4*)p; }
__device__ inline uint4 ld8(const float* p) {
    float4 a = *(const float4*)p;
    float4 b = *(const float4*)(p + 4);
    uint4 r;
    r.x = pack2(a.x, a.y); r.y = pack2(a.z, a.w);
    r.z = pack2(b.x, b.y); r.w = pack2(b.z, b.w);
    return r;
}

__device__ inline void gld16(const unsigned short* g, unsigned short* l) {
    __builtin_amdgcn_global_load_lds(
        (const __attribute__((address_space(1))) unsigned int*)g,
        (__attribute__((address_space(3))) unsigned int*)l, 16, 0, 0);
}

// fused fp32->bf16 conversion of x, qkv_w, proj_w (one launch)
__global__ __launch_bounds__(256) void cvt3_kernel(const float* __restrict__ x,
                                                   const float* __restrict__ qw,
                                                   const float* __restrict__ pw,
                                                   unsigned short* __restrict__ xb,
                                                   unsigned short* __restrict__ qwb,
                                                   unsigned short* __restrict__ pwb) {
    int i = blockIdx.x * blockDim.x + threadIdx.x;  // 0 .. 1048575
    const int NX = 4096 * 1024 / 8;      // 524288
    const int NQ = 3072 * 1024 / 8;      // 393216
    if (i < NX) {
        *(uint4*)(xb + (size_t)i * 8) = ld8(x + (size_t)i * 8);
    } else if (i < NX + NQ) {
        int j = i - NX;
        *(uint4*)(qwb + (size_t)j * 8) = ld8(qw + (size_t)j * 8);
    } else {
        int j = i - NX - NQ;
        *(uint4*)(pwb + (size_t)j * 8) = ld8(pw + (size_t)j * 8);
    }
}

// out[i] += part[i], 1 float4 per thread (4096 blocks x 256 threads)
__global__ __launch_bounds__(256) void addred_kernel(float4* __restrict__ out,
                                                     const float4* __restrict__ part) {
    int i = blockIdx.x * blockDim.x + threadIdx.x;
    float4 a = out[i];
    float4 b = part[i];
    a.x += b.x; a.y += b.y; a.z += b.z; a.w += b.w;
    out[i] = a;
}

// ---------------------------------------------------------------------------
// FAST GEMM (m97 recipe): all-bf16, (MT*32)x128 tile, BK=32, unpadded LDS,
// global_load_lds width-16 staging. C = A[M,K] * W[N,K]^T (+bias).
// XCD-swizzled block remap (requires gridX*gridY % 8 == 0).
// SPLITK==2: blockIdx.z selects the K/2 slice; kz=0 stores Cv (+bias),
// kz=1 stores fp32 partial to Cpart (reduced by addred_kernel afterwards).
// ---------------------------------------------------------------------------
template <int WITH_BIAS, int OUT_F32, int MT, int SPLITK>
__global__ __launch_bounds__(256) void gemm_fast(const unsigned short* __restrict__ A,
                                                 const unsigned short* __restrict__ W,
                                                 const float* __restrict__ bias,
                                                 void* __restrict__ Cv,
                                                 float* __restrict__ Cpart,
                                                 int M, int N, int K) {
    constexpr int BM = MT * 32;
    __shared__ unsigned short As[BM * 32];
    __shared__ unsigned short Bs[128 * 32];

    const int tid = threadIdx.x;
    const int wave = tid >> 6, lane = tid & 63;
    const int l15 = lane & 15, quad = lane >> 4;
    const int waveM = wave >> 1, waveN = wave & 1;

    // XCD swizzle: cluster consecutive work on one XCD's L2
    const int nbx = gridDim.x;
    const int L = blockIdx.y * nbx + blockIdx.x;
    const int nwg = nbx * gridDim.y;
    const int w = (L & 7) * (nwg >> 3) + (L >> 3);
    const int bm = (w / nbx) * BM, bn = (w % nbx) * 128;

    const int kz = (SPLITK > 1) ? blockIdx.z : 0;
    const int k0 = kz * (K / SPLITK), k1 = k0 + K / SPLITK;

    const int lr = lane >> 2;
    const int lc = (lane & 3) * 8;

    f32x4 acc[MT][4];
    for (int i = 0; i < MT; i++)
        for (int j = 0; j < 4; j++) acc[i][j] = (f32x4){0.f, 0.f, 0.f, 0.f};

    for (int kb = k0; kb < k1; kb += 32) {
        for (int p = 0; p < BM / 64; p++)
            gld16(A + (size_t)(bm + wave * (BM / 4) + p * 16 + lr) * K + kb + lc,
                  &As[(wave * (BM / 4) + p * 16) * 32]);
        gld16(W + (size_t)(bn + wave * 32 + lr) * K + kb + lc, &Bs[(wave * 32) * 32]);
        gld16(W + (size_t)(bn + wave * 32 + 16 + lr) * K + kb + lc, &Bs[(wave * 32 + 16) * 32]);
        __syncthreads();

        const int kcol = quad * 8;
        bf16x8 af[MT], bf[4];
        for (int mt = 0; mt < MT; mt++)
            af[mt] = *(const bf16x8*)(&As[(waveM * (MT * 16) + mt * 16 + l15) * 32 + kcol]);
        for (int nt = 0; nt < 4; nt++)
            bf[nt] = *(const bf16x8*)(&Bs[(waveN * 64 + nt * 16 + l15) * 32 + kcol]);
        for (int mt = 0; mt < MT; mt++)
            for (int nt = 0; nt < 4; nt++)
                acc[mt][nt] = __builtin_amdgcn_mfma_f32_16x16x32_bf16(af[mt], bf[nt], acc[mt][nt], 0, 0, 0);
        __syncthreads();
    }

    for (int mt = 0; mt < MT; mt++) {
        for (int nt = 0; nt < 4; nt++) {
            int col = bn + waveN * 64 + nt * 16 + l15;
            float bv = (WITH_BIAS && kz == 0) ? bias[col] : 0.f;
            for (int r = 0; r < 4; r++) {
                int row = bm + waveM * (MT * 16) + mt * 16 + quad * 4 + r;
                float v = acc[mt][nt][r] + bv;
                if (SPLITK > 1) {
                    float* dst = (kz == 0) ? (float*)Cv : Cpart;
                    dst[(size_t)row * N + col] = v;
                } else if (OUT_F32) {
                    ((float*)Cv)[(size_t)row * N + col] = v;
                } else {
                    ((unsigned short*)Cv)[(size_t)row * N + col] = f2bf(v);
                }
            }
        }
    }
}

// ---------------------------------------------------------------------------
// FALLBACK GEMM (R8): convert-in-staging, fp32/bf16 inputs.
// ---------------------------------------------------------------------------
template <int WITH_BIAS, int OUT_F32, typename TA, typename TW>
__global__ __launch_bounds__(256) void gemm_bt(const TA* __restrict__ A,
                                               const TW* __restrict__ W,
                                               const float* __restrict__ bias,
                                               void* __restrict__ Cv,
                                               int M, int N, int K) {
    const int LDSS = 40;
    __shared__ unsigned short As[128 * 40];
    __shared__ unsigned short Bs[128 * 40];

    const int tid = threadIdx.x;
    const int wave = tid >> 6, lane = tid & 63;
    const int l15 = lane & 15, quad = lane >> 4;
    const int waveM = wave >> 1, waveN = wave & 1;
    const int bm = blockIdx.y * 128, bn = blockIdx.x * 128;

    f32x4 acc[4][4];
    for (int i = 0; i < 4; i++)
        for (int j = 0; j < 4; j++) acc[i][j] = (f32x4){0.f, 0.f, 0.f, 0.f};

    for (int kb = 0; kb < K; kb += 32) {
        for (int c = tid; c < 512; c += 256) {
            int row = c >> 2, k0 = (c & 3) * 8;
            *(uint4*)(&As[row * LDSS + k0]) = ld8(A + (size_t)(bm + row) * K + kb + k0);
            *(uint4*)(&Bs[row * LDSS + k0]) = ld8(W + (size_t)(bn + row) * K + kb + k0);
        }
        __syncthreads();

        const int kcol = quad * 8;
        bf16x8 af[4], bf[4];
        for (int mt = 0; mt < 4; mt++)
            af[mt] = *(const bf16x8*)(&As[(waveM * 64 + mt * 16 + l15) * LDSS + kcol]);
        for (int nt = 0; nt < 4; nt++)
            bf[nt] = *(const bf16x8*)(&Bs[(waveN * 64 + nt * 16 + l15) * LDSS + kcol]);
        for (int mt = 0; mt < 4; mt++)
            for (int nt = 0; nt < 4; nt++)
                acc[mt][nt] = __builtin_amdgcn_mfma_f32_16x16x32_bf16(af[mt], bf[nt], acc[mt][nt], 0, 0, 0);
        __syncthreads();
    }

    for (int mt = 0; mt < 4; mt++) {
        for (int nt = 0; nt < 4; nt++) {
            int col = bn + waveN * 64 + nt * 16 + l15;
            float bv = WITH_BIAS ? bias[col] : 0.f;
            for (int r = 0; r < 4; r++) {
                int row = bm + waveM * 64 + mt * 16 + quad * 4 + r;
                float v = acc[mt][nt][r] + bv;
                if (OUT_F32) ((float*)Cv)[(size_t)row * N + col] = v;
                else ((unsigned short*)Cv)[(size_t)row * N + col] = f2bf(v);
            }
        }
    }
}

// ---------------------------------------------------------------------------
// Flash attention (R17, verified 49.8us): swapped-QK^T 32x32 MFMA,
// in-register P, XCD work-clustering (same-head q-tiles share an XCD L2).
// Block = 512 threads (8 waves) per (b, h, 128-q tile). Wave (qt, par).
// ---------------------------------------------------------------------------
__global__ __launch_bounds__(512, 4) void attn_kernel(const unsigned short* __restrict__ qkv,
                                                      unsigned short* __restrict__ y) {
    // bijective XCD clustering over 512 blocks: XCD k gets contiguous work ids
    const int L = blockIdx.x + 16 * (blockIdx.y + 16 * blockIdx.z);
    const int wid = (L & 7) * 64 + (L >> 3);
    const int q0 = (wid & 15) * 128;
    const int head = wid >> 4;            // 0..31
    const int h = head & 15, b = head >> 4;

    const int tid = threadIdx.x;
    const int wave = tid >> 6, lane = tid & 63;
    const int l31 = lane & 31, half = lane >> 5;
    const int qt = wave >> 1, par = wave & 1;

    // LDS: staging Ks[128][64] + Vt[64][128] (32 KiB), reused as combine
    // buffers (obuf 4x2048 f32 + lbuf 4x32 f32 = 33280 B) after the loop.
    __shared__ __align__(16) unsigned short smem[16640];
    unsigned short* Ks = smem;           // 8192 shorts
    unsigned short* Vt = smem + 8192;    // 8192 shorts

    const size_t bbase = (size_t)b * 2048;
    const float C = 0.18033688f;  // 0.125 * log2(e)

    // ---- Q fragments (B operand), pre-scaled, straight from global ----
    bf16x8 qf[4];
    {
        const unsigned short* qrow =
            qkv + (bbase + q0 + qt * 32 + l31) * 3072 + h * 64 + half * 8;
        #pragma unroll
        for (int t = 0; t < 4; t++) {
            uint4 v = *(const uint4*)(qrow + t * 16);
            const unsigned short* pv = (const unsigned short*)&v;
            union { bf16x8 v8; unsigned int u[4]; } o;
            #pragma unroll
            for (int j = 0; j < 4; j++)
                o.u[j] = pack2(bf2f(pv[2 * j]) * C, bf2f(pv[2 * j + 1]) * C);
            qf[t] = o.v8;
        }
    }

    // ---- staging coords ----
    const int kr = tid >> 3;     // 0..63: K row (and +64); V key-pair index
    const int cb = tid & 7;      // 16B column block (K) / d-group (V)
    const int sk = (kr ^ (kr >> 3)) & 7;            // K swizzle (same for kr+64)
    const unsigned short* kptr = qkv + (bbase + kr) * 3072 + h * 64 + 1024 + cb * 8;
    const unsigned short* vptr = qkv + (bbase + 2 * kr) * 3072 + h * 64 + 2048 + cb * 8;

    f32x16 o[2];
    #pragma unroll
    for (int j = 0; j < 16; j++) { o[0][j] = 0.f; o[1][j] = 0.f; }
    float Lp = 0.f;

    // prefetch chunk 0
    uint4 kA0 = *(const uint4*)(kptr);
    uint4 kA1 = *(const uint4*)(kptr + (size_t)64 * 3072);
    uint4 vA0 = *(const uint4*)(vptr);
    uint4 vA1 = *(const uint4*)(vptr + 3072);

    for (int kb = 0; kb < 2048; kb += 128) {
        __syncthreads();  // previous chunk's LDS consumers done

        // commit prefetched K (swizzled 16B blocks)
        *(uint4*)(&Ks[kr * 64 + ((cb ^ sk) * 8)]) = kA0;
        *(uint4*)(&Ks[(kr + 64) * 64 + ((cb ^ sk) * 8)]) = kA1;
        // commit prefetched V, transposed: Vt[d][key], swizzled dwords
        {
            const unsigned short* p0 = (const unsigned short*)&vA0;
            const unsigned short* p1 = (const unsigned short*)&vA1;
            #pragma unroll
            for (int j = 0; j < 8; j++) {
                unsigned int w = (unsigned int)p0[j] | ((unsigned int)p1[j] << 16);
                *(unsigned int*)(&Vt[(cb * 8 + j) * 128 + ((2 * kr) ^ ((j ^ cb) * 8))]) = w;
            }
        }
        __syncthreads();

        // prefetch next chunk (loads in flight across compute below)
        int nkb = (kb + 128) & 2047;
        size_t koff = (size_t)nkb * 3072;
        kA0 = *(const uint4*)(kptr + koff);
        kA1 = *(const uint4*)(kptr + koff + (size_t)64 * 3072);
        vA0 = *(const uint4*)(vptr + koff);
        vA1 = *(const uint4*)(vptr + koff + 3072);

        // two 32-key chunks from this wave's key-half
        #pragma unroll
        for (int ci = 0; ci < 2; ci++) {
            const int kc = (par * 2 + ci) * 32;

            // ---- S^T = K * Q^T : lane -> P row for q = l31 ----
            const int key = kc + l31;
            const int skk = (key ^ (key >> 3)) & 7;
            const unsigned short* kbase = &Ks[key * 64];
            f32x16 s;
            #pragma unroll
            for (int j = 0; j < 16; j++) s[j] = 0.f;
            __builtin_amdgcn_s_setprio(1);
            #pragma unroll
            for (int t = 0; t < 4; t++) {
                bf16x8 kf = *(const bf16x8*)(kbase + (((t * 2 + half) ^ skk) * 8));
                s = __builtin_amdgcn_mfma_f32_32x32x16_bf16(kf, qf[t], s, 0, 0, 0);
            }
            __builtin_amdgcn_s_setprio(0);

            // ---- p = 2^s (unnormalized), l partial via VALU tree ----
            float p[16];
            #pragma unroll
            for (int r = 0; r < 16; r++) p[r] = EXP2F(s[r]);
            {
                float t0 = (p[0] + p[1]) + (p[2] + p[3]);
                float t1 = (p[4] + p[5]) + (p[6] + p[7]);
                float t2 = (p[8] + p[9]) + (p[10] + p[11]);
                float t3 = (p[12] + p[13]) + (p[14] + p[15]);
                Lp += (t0 + t1) + (t2 + t3);
            }

            // ---- pack to bf16 + permlane32_swap => PV A-fragments ----
            unsigned int a0, a1, a2, a3, a4, a5, a6, a7;
            asm("v_cvt_pk_bf16_f32 %0, %1, %2" : "=v"(a0) : "v"(p[0]), "v"(p[1]));
            asm("v_cvt_pk_bf16_f32 %0, %1, %2" : "=v"(a1) : "v"(p[2]), "v"(p[3]));
            asm("v_cvt_pk_bf16_f32 %0, %1, %2" : "=v"(a2) : "v"(p[4]), "v"(p[5]));
            asm("v_cvt_pk_bf16_f32 %0, %1, %2" : "=v"(a3) : "v"(p[6]), "v"(p[7]));
            asm("v_cvt_pk_bf16_f32 %0, %1, %2" : "=v"(a4) : "v"(p[8]), "v"(p[9]));
            asm("v_cvt_pk_bf16_f32 %0, %1, %2" : "=v"(a5) : "v"(p[10]), "v"(p[11]));
            asm("v_cvt_pk_bf16_f32 %0, %1, %2" : "=v"(a6) : "v"(p[12]), "v"(p[13]));
            asm("v_cvt_pk_bf16_f32 %0, %1, %2" : "=v"(a7) : "v"(p[14]), "v"(p[15]));
            asm("v_permlane32_swap_b32 %0, %1" : "+v"(a0), "+v"(a2));
            asm("v_permlane32_swap_b32 %0, %1" : "+v"(a1), "+v"(a3));
            asm("v_permlane32_swap_b32 %0, %1" : "+v"(a4), "+v"(a6));
            asm("v_permlane32_swap_b32 %0, %1" : "+v"(a5), "+v"(a7));
            union { bf16x8 v8; unsigned int u[4]; } f1, f2;
            f1.u[0] = a0; f1.u[1] = a1; f1.u[2] = a2; f1.u[3] = a3;
            f2.u[0] = a4; f2.u[1] = a5; f2.u[2] = a6; f2.u[3] = a7;

            // ---- O += P * V ----
            __builtin_amdgcn_s_setprio(1);
            #pragma unroll
            for (int dt = 0; dt < 2; dt++) {
                const int row = dt * 32 + l31;
                const int sv = (row ^ (row >> 3)) & 7;
                const unsigned short* vb = &Vt[row * 128];
                bf16x8 v0 = *(const bf16x8*)(vb + ((((kc >> 3) + half) ^ sv) * 8));
                bf16x8 v1 = *(const bf16x8*)(vb + ((((kc >> 3) + 2 + half) ^ sv) * 8));
                o[dt] = __builtin_amdgcn_mfma_f32_32x32x16_bf16(f1.v8, v0, o[dt], 0, 0, 0);
                o[dt] = __builtin_amdgcn_mfma_f32_32x32x16_bf16(f2.v8, v1, o[dt], 0, 0, 0);
            }
            __builtin_amdgcn_s_setprio(0);
        }
    }

    // ---- l: sum both lane-halves (q = l31 at every lane afterwards) ----
    float lx = Lp, ly = Lp;
    asm("v_permlane32_swap_b32 %0, %1" : "+v"(lx), "+v"(ly));
    float ltot31 = lx + ly;

    // ---- combine par=0 / par=1 partials through LDS ----
    __syncthreads();  // staging LDS no longer needed
    float* obuf = (float*)smem;                 // 4 x 2048 floats
    float* lbuf = ((float*)smem) + 8192;        // 4 x 32 floats
    if (par == 0) {
        float* ob = obuf + qt * 2048;
        #pragma unroll
        for (int dt = 0; dt < 2; dt++)
            #pragma unroll
            for (int r = 0; r < 16; r++) {
                int ql = (r & 3) + 8 * (r >> 2) + 4 * half;
                ob[ql * 64 + dt * 32 + l31] = o[dt][r];
            }
        if (half == 0) lbuf[qt * 32 + l31] = ltot31;
    }
    __syncthreads();
    if (par == 1) {
        const float* ob = obuf + qt * 2048;
        #pragma unroll
        for (int r = 0; r < 16; r++) {
            int ql = (r & 3) + 8 * (r >> 2) + 4 * half;
            float lsum = lbuf[qt * 32 + ql] + __shfl(ltot31, ql, 64);
            float rl = 1.0f / lsum;
            int row = q0 + qt * 32 + ql;
            #pragma unroll
            for (int dt = 0; dt < 2; dt++) {
                float v = ob[ql * 64 + dt * 32 + l31] + o[dt][r];
                y[(bbase + row) * 1024 + h * 64 + dt * 32 + l31] = f2bf(v * rl);
            }
        }
    }
}

extern "C" void kernel_launch(void* const* d_in, const int* in_sizes, int n_in,
                              void* d_out, int out_size, void* d_ws, size_t ws_size,
                              hipStream_t stream) {
    const float* x = (const float*)d_in[0];       // [4096,1024] fp32
    const float* qkv_w = (const float*)d_in[1];   // [3072,1024] fp32
    const float* proj_w = (const float*)d_in[2];  // [1024,1024] fp32
    const float* proj_b = (const float*)d_in[3];  // [1024] fp32
    float* out = (float*)d_out;                   // [4096,1024] fp32

    unsigned short* qkv = (unsigned short*)d_ws;               // 24 MiB
    unsigned short* slot2 = qkv + (size_t)4096 * 3072;         // 8 MiB: x_bf then y

    const size_t FAST_WS = (size_t)40 * 1024 * 1024;
    if (ws_size >= FAST_WS) {
        unsigned short* xb = slot2;                             // dead after qkv GEMM
        unsigned short* qwb = (unsigned short*)((char*)d_ws + 32 * 1024 * 1024);  // 6 MiB
        unsigned short* pwb = (unsigned short*)((char*)d_ws + 38 * 1024 * 1024);  // 2 MiB
        unsigned short* y = slot2;
        float* part = (float*)d_ws;   // proj split-K partial: qkv region, dead after attn

        cvt3_kernel<<<4096, 256, 0, stream>>>(x, qkv_w, proj_w, xb, qwb, pwb);

        gemm_fast<0, 0, 4, 1><<<dim3(24, 32), dim3(256), 0, stream>>>(
            xb, qwb, nullptr, qkv, nullptr, 4096, 3072, 1024);
        attn_kernel<<<dim3(16, 16, 2), dim3(512), 0, stream>>>(qkv, y);
        gemm_fast<1, 1, 4, 2><<<dim3(8, 32, 2), dim3(256), 0, stream>>>(
            y, pwb, proj_b, out, part, 4096, 1024, 1024);
        addred_kernel<<<4096, 256, 0, stream>>>((float4*)out, (const float4*)part);
    } else {
        unsigned short* y = slot2;
        gemm_bt<0, 0, float, float><<<dim3(24, 32), dim3(256), 0, stream>>>(
            x, qkv_w, nullptr, qkv, 4096, 3072, 1024);
        attn_kernel<<<dim3(16, 16, 2), dim3(512), 0, stream>>>(qkv, y);
        gemm_bt<1, 1, unsigned short, float><<<dim3(8, 32), dim3(256), 0, stream>>>(
            y, proj_w, proj_b, out, 4096, 1024, 1024);
    }
}

// Round 12
// 182.724 us; speedup vs baseline: 1.1025x; 1.0510x over previous
//
#include <hip/hip_runtime.h>

// SelfAttention: x[2,2048,1024] fp32 -> qkv -> flash attention -> proj -> fp32.
// R23 == R20 (final, verified 187.1us): the session's best configuration.
// - attn (R17): swapped-QK^T 32x32 MFMA, in-register P (cvt_pk+permlane32),
//   XOR-swizzled K/Vt, XCD work-clustering (FETCH 74->13MB). 49.7us.
// - qkv: m97-recipe gemm_fast BK=32 MT=4, XCD swizzle, 768 blocks.
// - proj: gemm_fast BK=32 MT=2, 512 blocks (2/CU).
// Retired branches (mechanisms identified): deep-pipeline attn (allocator
// pins 64 VGPR + spills), occupancy split (register-capped), BK=64 (128B-
// stride bank conflicts), split-K atomics (~25us L2 RMW), split-K +reduce
// (+5us reduce overhead).

typedef __bf16 bf16x8 __attribute__((ext_vector_type(8)));
typedef float f32x4 __attribute__((ext_vector_type(4)));
typedef float f32x16 __attribute__((ext_vector_type(16)));

#if __has_builtin(__builtin_amdgcn_exp2f)
#define EXP2F(x) __builtin_amdgcn_exp2f(x)
#else
#define EXP2F(x) __expf((x)*0.69314718056f)
#endif

__device__ inline float bf2f(unsigned short u) {
    union { unsigned int i; float f; } v; v.i = ((unsigned int)u) << 16; return v.f;
}
__device__ inline unsigned short f2bf(float f) {
    union { float f; unsigned int i; } v; v.f = f;
    unsigned int u = v.i;
    return (unsigned short)((u + 0x7FFFu + ((u >> 16) & 1u)) >> 16);  // RNE
}
__device__ inline unsigned int pack2(float lo, float hi) {
    return (unsigned int)f2bf(lo) | ((unsigned int)f2bf(hi) << 16);
}
__device__ inline uint4 ld8(const unsigned short* p) { return *(const uint4*)p; }
__device__ inline uint4 ld8(const float* p) {
    float4 a = *(const float4*)p;
    float4 b = *(const float4*)(p + 4);
    uint4 r;
    r.x = pack2(a.x, a.y); r.y = pack2(a.z, a.w);
    r.z = pack2(b.x, b.y); r.w = pack2(b.z, b.w);
    return r;
}

__device__ inline void gld16(const unsigned short* g, unsigned short* l) {
    __builtin_amdgcn_global_load_lds(
        (const __attribute__((address_space(1))) unsigned int*)g,
        (__attribute__((address_space(3))) unsigned int*)l, 16, 0, 0);
}

// fused fp32->bf16 conversion of x, qkv_w, proj_w (one launch)
__global__ __launch_bounds__(256) void cvt3_kernel(const float* __restrict__ x,
                                                   const float* __restrict__ qw,
                                                   const float* __restrict__ pw,
                                                   unsigned short* __restrict__ xb,
                                                   unsigned short* __restrict__ qwb,
                                                   unsigned short* __restrict__ pwb) {
    int i = blockIdx.x * blockDim.x + threadIdx.x;  // 0 .. 1048575
    const int NX = 4096 * 1024 / 8;      // 524288
    const int NQ = 3072 * 1024 / 8;      // 393216
    if (i < NX) {
        *(uint4*)(xb + (size_t)i * 8) = ld8(x + (size_t)i * 8);
    } else if (i < NX + NQ) {
        int j = i - NX;
        *(uint4*)(qwb + (size_t)j * 8) = ld8(qw + (size_t)j * 8);
    } else {
        int j = i - NX - NQ;
        *(uint4*)(pwb + (size_t)j * 8) = ld8(pw + (size_t)j * 8);
    }
}

// ---------------------------------------------------------------------------
// FAST GEMM (m97 recipe): all-bf16, (MT*32)x128 tile, BK=32, unpadded LDS,
// global_load_lds width-16 staging. C = A[M,K] * W[N,K]^T (+bias).
// XCD-swizzled block remap (requires gridX*gridY % 8 == 0).
// ---------------------------------------------------------------------------
template <int WITH_BIAS, int OUT_F32, int MT>
__global__ __launch_bounds__(256) void gemm_fast(const unsigned short* __restrict__ A,
                                                 const unsigned short* __restrict__ W,
                                                 const float* __restrict__ bias,
                                                 void* __restrict__ Cv,
                                                 int M, int N, int K) {
    constexpr int BM = MT * 32;
    __shared__ unsigned short As[BM * 32];
    __shared__ unsigned short Bs[128 * 32];

    const int tid = threadIdx.x;
    const int wave = tid >> 6, lane = tid & 63;
    const int l15 = lane & 15, quad = lane >> 4;
    const int waveM = wave >> 1, waveN = wave & 1;

    // XCD swizzle: cluster consecutive work on one XCD's L2
    const int nbx = gridDim.x;
    const int L = blockIdx.y * nbx + blockIdx.x;
    const int nwg = nbx * gridDim.y;
    const int w = (L & 7) * (nwg >> 3) + (L >> 3);
    const int bm = (w / nbx) * BM, bn = (w % nbx) * 128;

    const int lr = lane >> 2;
    const int lc = (lane & 3) * 8;

    f32x4 acc[MT][4];
    for (int i = 0; i < MT; i++)
        for (int j = 0; j < 4; j++) acc[i][j] = (f32x4){0.f, 0.f, 0.f, 0.f};

    for (int kb = 0; kb < K; kb += 32) {
        for (int p = 0; p < BM / 64; p++)
            gld16(A + (size_t)(bm + wave * (BM / 4) + p * 16 + lr) * K + kb + lc,
                  &As[(wave * (BM / 4) + p * 16) * 32]);
        gld16(W + (size_t)(bn + wave * 32 + lr) * K + kb + lc, &Bs[(wave * 32) * 32]);
        gld16(W + (size_t)(bn + wave * 32 + 16 + lr) * K + kb + lc, &Bs[(wave * 32 + 16) * 32]);
        __syncthreads();

        const int kcol = quad * 8;
        bf16x8 af[MT], bf[4];
        for (int mt = 0; mt < MT; mt++)
            af[mt] = *(const bf16x8*)(&As[(waveM * (MT * 16) + mt * 16 + l15) * 32 + kcol]);
        for (int nt = 0; nt < 4; nt++)
            bf[nt] = *(const bf16x8*)(&Bs[(waveN * 64 + nt * 16 + l15) * 32 + kcol]);
        for (int mt = 0; mt < MT; mt++)
            for (int nt = 0; nt < 4; nt++)
                acc[mt][nt] = __builtin_amdgcn_mfma_f32_16x16x32_bf16(af[mt], bf[nt], acc[mt][nt], 0, 0, 0);
        __syncthreads();
    }

    for (int mt = 0; mt < MT; mt++) {
        for (int nt = 0; nt < 4; nt++) {
            int col = bn + waveN * 64 + nt * 16 + l15;
            float bv = WITH_BIAS ? bias[col] : 0.f;
            for (int r = 0; r < 4; r++) {
                int row = bm + waveM * (MT * 16) + mt * 16 + quad * 4 + r;
                float v = acc[mt][nt][r] + bv;
                if (OUT_F32) ((float*)Cv)[(size_t)row * N + col] = v;
                else ((unsigned short*)Cv)[(size_t)row * N + col] = f2bf(v);
            }
        }
    }
}

// ---------------------------------------------------------------------------
// FALLBACK GEMM (R8): convert-in-staging, fp32/bf16 inputs.
// ---------------------------------------------------------------------------
template <int WITH_BIAS, int OUT_F32, typename TA, typename TW>
__global__ __launch_bounds__(256) void gemm_bt(const TA* __restrict__ A,
                                               const TW* __restrict__ W,
                                               const float* __restrict__ bias,
                                               void* __restrict__ Cv,
                                               int M, int N, int K) {
    const int LDSS = 40;
    __shared__ unsigned short As[128 * 40];
    __shared__ unsigned short Bs[128 * 40];

    const int tid = threadIdx.x;
    const int wave = tid >> 6, lane = tid & 63;
    const int l15 = lane & 15, quad = lane >> 4;
    const int waveM = wave >> 1, waveN = wave & 1;
    const int bm = blockIdx.y * 128, bn = blockIdx.x * 128;

    f32x4 acc[4][4];
    for (int i = 0; i < 4; i++)
        for (int j = 0; j < 4; j++) acc[i][j] = (f32x4){0.f, 0.f, 0.f, 0.f};

    for (int kb = 0; kb < K; kb += 32) {
        for (int c = tid; c < 512; c += 256) {
            int row = c >> 2, k0 = (c & 3) * 8;
            *(uint4*)(&As[row * LDSS + k0]) = ld8(A + (size_t)(bm + row) * K + kb + k0);
            *(uint4*)(&Bs[row * LDSS + k0]) = ld8(W + (size_t)(bn + row) * K + kb + k0);
        }
        __syncthreads();

        const int kcol = quad * 8;
        bf16x8 af[4], bf[4];
        for (int mt = 0; mt < 4; mt++)
            af[mt] = *(const bf16x8*)(&As[(waveM * 64 + mt * 16 + l15) * LDSS + kcol]);
        for (int nt = 0; nt < 4; nt++)
            bf[nt] = *(const bf16x8*)(&Bs[(waveN * 64 + nt * 16 + l15) * LDSS + kcol]);
        for (int mt = 0; mt < 4; mt++)
            for (int nt = 0; nt < 4; nt++)
                acc[mt][nt] = __builtin_amdgcn_mfma_f32_16x16x32_bf16(af[mt], bf[nt], acc[mt][nt], 0, 0, 0);
        __syncthreads();
    }

    for (int mt = 0; mt < 4; mt++) {
        for (int nt = 0; nt < 4; nt++) {
            int col = bn + waveN * 64 + nt * 16 + l15;
            float bv = WITH_BIAS ? bias[col] : 0.f;
            for (int r = 0; r < 4; r++) {
                int row = bm + waveM * 64 + mt * 16 + quad * 4 + r;
                float v = acc[mt][nt][r] + bv;
                if (OUT_F32) ((float*)Cv)[(size_t)row * N + col] = v;
                else ((unsigned short*)Cv)[(size_t)row * N + col] = f2bf(v);
            }
        }
    }
}

// ---------------------------------------------------------------------------
// Flash attention (R17, verified 49.8us): swapped-QK^T 32x32 MFMA,
// in-register P, XCD work-clustering (same-head q-tiles share an XCD L2).
// Block = 512 threads (8 waves) per (b, h, 128-q tile). Wave (qt, par).
// ---------------------------------------------------------------------------
__global__ __launch_bounds__(512, 4) void attn_kernel(const unsigned short* __restrict__ qkv,
                                                      unsigned short* __restrict__ y) {
    // bijective XCD clustering over 512 blocks: XCD k gets contiguous work ids
    const int L = blockIdx.x + 16 * (blockIdx.y + 16 * blockIdx.z);
    const int wid = (L & 7) * 64 + (L >> 3);
    const int q0 = (wid & 15) * 128;
    const int head = wid >> 4;            // 0..31
    const int h = head & 15, b = head >> 4;

    const int tid = threadIdx.x;
    const int wave = tid >> 6, lane = tid & 63;
    const int l31 = lane & 31, half = lane >> 5;
    const int qt = wave >> 1, par = wave & 1;

    // LDS: staging Ks[128][64] + Vt[64][128] (32 KiB), reused as combine
    // buffers (obuf 4x2048 f32 + lbuf 4x32 f32 = 33280 B) after the loop.
    __shared__ __align__(16) unsigned short smem[16640];
    unsigned short* Ks = smem;           // 8192 shorts
    unsigned short* Vt = smem + 8192;    // 8192 shorts

    const size_t bbase = (size_t)b * 2048;
    const float C = 0.18033688f;  // 0.125 * log2(e)

    // ---- Q fragments (B operand), pre-scaled, straight from global ----
    bf16x8 qf[4];
    {
        const unsigned short* qrow =
            qkv + (bbase + q0 + qt * 32 + l31) * 3072 + h * 64 + half * 8;
        #pragma unroll
        for (int t = 0; t < 4; t++) {
            uint4 v = *(const uint4*)(qrow + t * 16);
            const unsigned short* pv = (const unsigned short*)&v;
            union { bf16x8 v8; unsigned int u[4]; } o;
            #pragma unroll
            for (int j = 0; j < 4; j++)
                o.u[j] = pack2(bf2f(pv[2 * j]) * C, bf2f(pv[2 * j + 1]) * C);
            qf[t] = o.v8;
        }
    }

    // ---- staging coords ----
    const int kr = tid >> 3;     // 0..63: K row (and +64); V key-pair index
    const int cb = tid & 7;      // 16B column block (K) / d-group (V)
    const int sk = (kr ^ (kr >> 3)) & 7;            // K swizzle (same for kr+64)
    const unsigned short* kptr = qkv + (bbase + kr) * 3072 + h * 64 + 1024 + cb * 8;
    const unsigned short* vptr = qkv + (bbase + 2 * kr) * 3072 + h * 64 + 2048 + cb * 8;

    f32x16 o[2];
    #pragma unroll
    for (int j = 0; j < 16; j++) { o[0][j] = 0.f; o[1][j] = 0.f; }
    float Lp = 0.f;

    // prefetch chunk 0
    uint4 kA0 = *(const uint4*)(kptr);
    uint4 kA1 = *(const uint4*)(kptr + (size_t)64 * 3072);
    uint4 vA0 = *(const uint4*)(vptr);
    uint4 vA1 = *(const uint4*)(vptr + 3072);

    for (int kb = 0; kb < 2048; kb += 128) {
        __syncthreads();  // previous chunk's LDS consumers done

        // commit prefetched K (swizzled 16B blocks)
        *(uint4*)(&Ks[kr * 64 + ((cb ^ sk) * 8)]) = kA0;
        *(uint4*)(&Ks[(kr + 64) * 64 + ((cb ^ sk) * 8)]) = kA1;
        // commit prefetched V, transposed: Vt[d][key], swizzled dwords
        {
            const unsigned short* p0 = (const unsigned short*)&vA0;
            const unsigned short* p1 = (const unsigned short*)&vA1;
            #pragma unroll
            for (int j = 0; j < 8; j++) {
                unsigned int w = (unsigned int)p0[j] | ((unsigned int)p1[j] << 16);
                *(unsigned int*)(&Vt[(cb * 8 + j) * 128 + ((2 * kr) ^ ((j ^ cb) * 8))]) = w;
            }
        }
        __syncthreads();

        // prefetch next chunk (loads in flight across compute below)
        int nkb = (kb + 128) & 2047;
        size_t koff = (size_t)nkb * 3072;
        kA0 = *(const uint4*)(kptr + koff);
        kA1 = *(const uint4*)(kptr + koff + (size_t)64 * 3072);
        vA0 = *(const uint4*)(vptr + koff);
        vA1 = *(const uint4*)(vptr + koff + 3072);

        // two 32-key chunks from this wave's key-half
        #pragma unroll
        for (int ci = 0; ci < 2; ci++) {
            const int kc = (par * 2 + ci) * 32;

            // ---- S^T = K * Q^T : lane -> P row for q = l31 ----
            const int key = kc + l31;
            const int skk = (key ^ (key >> 3)) & 7;
            const unsigned short* kbase = &Ks[key * 64];
            f32x16 s;
            #pragma unroll
            for (int j = 0; j < 16; j++) s[j] = 0.f;
            __builtin_amdgcn_s_setprio(1);
            #pragma unroll
            for (int t = 0; t < 4; t++) {
                bf16x8 kf = *(const bf16x8*)(kbase + (((t * 2 + half) ^ skk) * 8));
                s = __builtin_amdgcn_mfma_f32_32x32x16_bf16(kf, qf[t], s, 0, 0, 0);
            }
            __builtin_amdgcn_s_setprio(0);

            // ---- p = 2^s (unnormalized), l partial via VALU tree ----
            float p[16];
            #pragma unroll
            for (int r = 0; r < 16; r++) p[r] = EXP2F(s[r]);
            {
                float t0 = (p[0] + p[1]) + (p[2] + p[3]);
                float t1 = (p[4] + p[5]) + (p[6] + p[7]);
                float t2 = (p[8] + p[9]) + (p[10] + p[11]);
                float t3 = (p[12] + p[13]) + (p[14] + p[15]);
                Lp += (t0 + t1) + (t2 + t3);
            }

            // ---- pack to bf16 + permlane32_swap => PV A-fragments ----
            unsigned int a0, a1, a2, a3, a4, a5, a6, a7;
            asm("v_cvt_pk_bf16_f32 %0, %1, %2" : "=v"(a0) : "v"(p[0]), "v"(p[1]));
            asm("v_cvt_pk_bf16_f32 %0, %1, %2" : "=v"(a1) : "v"(p[2]), "v"(p[3]));
            asm("v_cvt_pk_bf16_f32 %0, %1, %2" : "=v"(a2) : "v"(p[4]), "v"(p[5]));
            asm("v_cvt_pk_bf16_f32 %0, %1, %2" : "=v"(a3) : "v"(p[6]), "v"(p[7]));
            asm("v_cvt_pk_bf16_f32 %0, %1, %2" : "=v"(a4) : "v"(p[8]), "v"(p[9]));
            asm("v_cvt_pk_bf16_f32 %0, %1, %2" : "=v"(a5) : "v"(p[10]), "v"(p[11]));
            asm("v_cvt_pk_bf16_f32 %0, %1, %2" : "=v"(a6) : "v"(p[12]), "v"(p[13]));
            asm("v_cvt_pk_bf16_f32 %0, %1, %2" : "=v"(a7) : "v"(p[14]), "v"(p[15]));
            asm("v_permlane32_swap_b32 %0, %1" : "+v"(a0), "+v"(a2));
            asm("v_permlane32_swap_b32 %0, %1" : "+v"(a1), "+v"(a3));
            asm("v_permlane32_swap_b32 %0, %1" : "+v"(a4), "+v"(a6));
            asm("v_permlane32_swap_b32 %0, %1" : "+v"(a5), "+v"(a7));
            union { bf16x8 v8; unsigned int u[4]; } f1, f2;
            f1.u[0] = a0; f1.u[1] = a1; f1.u[2] = a2; f1.u[3] = a3;
            f2.u[0] = a4; f2.u[1] = a5; f2.u[2] = a6; f2.u[3] = a7;

            // ---- O += P * V ----
            __builtin_amdgcn_s_setprio(1);
            #pragma unroll
            for (int dt = 0; dt < 2; dt++) {
                const int row = dt * 32 + l31;
                const int sv = (row ^ (row >> 3)) & 7;
                const unsigned short* vb = &Vt[row * 128];
                bf16x8 v0 = *(const bf16x8*)(vb + ((((kc >> 3) + half) ^ sv) * 8));
                bf16x8 v1 = *(const bf16x8*)(vb + ((((kc >> 3) + 2 + half) ^ sv) * 8));
                o[dt] = __builtin_amdgcn_mfma_f32_32x32x16_bf16(f1.v8, v0, o[dt], 0, 0, 0);
                o[dt] = __builtin_amdgcn_mfma_f32_32x32x16_bf16(f2.v8, v1, o[dt], 0, 0, 0);
            }
            __builtin_amdgcn_s_setprio(0);
        }
    }

    // ---- l: sum both lane-halves (q = l31 at every lane afterwards) ----
    float lx = Lp, ly = Lp;
    asm("v_permlane32_swap_b32 %0, %1" : "+v"(lx), "+v"(ly));
    float ltot31 = lx + ly;

    // ---- combine par=0 / par=1 partials through LDS ----
    __syncthreads();  // staging LDS no longer needed
    float* obuf = (float*)smem;                 // 4 x 2048 floats
    float* lbuf = ((float*)smem) + 8192;        // 4 x 32 floats
    if (par == 0) {
        float* ob = obuf + qt * 2048;
        #pragma unroll
        for (int dt = 0; dt < 2; dt++)
            #pragma unroll
            for (int r = 0; r < 16; r++) {
                int ql = (r & 3) + 8 * (r >> 2) + 4 * half;
                ob[ql * 64 + dt * 32 + l31] = o[dt][r];
            }
        if (half == 0) lbuf[qt * 32 + l31] = ltot31;
    }
    __syncthreads();
    if (par == 1) {
        const float* ob = obuf + qt * 2048;
        #pragma unroll
        for (int r = 0; r < 16; r++) {
            int ql = (r & 3) + 8 * (r >> 2) + 4 * half;
            float lsum = lbuf[qt * 32 + ql] + __shfl(ltot31, ql, 64);
            float rl = 1.0f / lsum;
            int row = q0 + qt * 32 + ql;
            #pragma unroll
            for (int dt = 0; dt < 2; dt++) {
                float v = ob[ql * 64 + dt * 32 + l31] + o[dt][r];
                y[(bbase + row) * 1024 + h * 64 + dt * 32 + l31] = f2bf(v * rl);
            }
        }
    }
}

extern "C" void kernel_launch(void* const* d_in, const int* in_sizes, int n_in,
                              void* d_out, int out_size, void* d_ws, size_t ws_size,
                              hipStream_t stream) {
    const float* x = (const float*)d_in[0];       // [4096,1024] fp32
    const float* qkv_w = (const float*)d_in[1];   // [3072,1024] fp32
    const float* proj_w = (const float*)d_in[2];  // [1024,1024] fp32
    const float* proj_b = (const float*)d_in[3];  // [1024] fp32
    float* out = (float*)d_out;                   // [4096,1024] fp32

    unsigned short* qkv = (unsigned short*)d_ws;               // 24 MiB
    unsigned short* slot2 = qkv + (size_t)4096 * 3072;         // 8 MiB: x_bf then y

    const size_t FAST_WS = (size_t)40 * 1024 * 1024;
    if (ws_size >= FAST_WS) {
        unsigned short* xb = slot2;                             // dead after qkv GEMM
        unsigned short* qwb = (unsigned short*)((char*)d_ws + 32 * 1024 * 1024);  // 6 MiB
        unsigned short* pwb = (unsigned short*)((char*)d_ws + 38 * 1024 * 1024);  // 2 MiB
        unsigned short* y = slot2;

        cvt3_kernel<<<4096, 256, 0, stream>>>(x, qkv_w, proj_w, xb, qwb, pwb);

        gemm_fast<0, 0, 4><<<dim3(24, 32), dim3(256), 0, stream>>>(
            xb, qwb, nullptr, qkv, 4096, 3072, 1024);
        attn_kernel<<<dim3(16, 16, 2), dim3(512), 0, stream>>>(qkv, y);
        gemm_fast<1, 1, 2><<<dim3(8, 64), dim3(256), 0, stream>>>(
            y, pwb, proj_b, out, 4096, 1024, 1024);
    } else {
        unsigned short* y = slot2;
        gemm_bt<0, 0, float, float><<<dim3(24, 32), dim3(256), 0, stream>>>(
            x, qkv_w, nullptr, qkv, 4096, 3072, 1024);
        attn_kernel<<<dim3(16, 16, 2), dim3(512), 0, stream>>>(qkv, y);
        gemm_bt<1, 1, unsigned short, float><<<dim3(8, 32), dim3(256), 0, stream>>>(
            y, proj_w, proj_b, out, 4096, 1024, 1024);
    }
}